// Round 14
// baseline (331.143 us; speedup 1.0000x reference)
//
#include <hip/hip_runtime.h>
#include <stdint.h>

typedef float f32x4 __attribute__((ext_vector_type(4)));
typedef __bf16 bf16x8 __attribute__((ext_vector_type(8)));

#define LOG2E 1.4426950408889634f
#define SCL2 (0.125f * LOG2E)   // 1/sqrt(64) * log2(e), folded into Q at GEMM epilogue

// RNE float -> bf16 bits (values are finite; NaN path not needed)
static __device__ __forceinline__ unsigned short f2bf(float f) {
  unsigned int u = __builtin_bit_cast(unsigned int, f);
  u += 0x7fffu + ((u >> 16) & 1u);
  return (unsigned short)(u >> 16);
}

static __device__ __forceinline__ void gload16(const void* g, void* l) {
  __builtin_amdgcn_global_load_lds(
      (const __attribute__((address_space(1))) unsigned int*)g,
      (__attribute__((address_space(3))) unsigned int*)l, 16, 0, 0);
}

// ---------------- kernel 1: fused {x fp32->bf16} + {W transpose->bf16} ----------------
__global__ void prep_kernel(const float* __restrict__ x, const float* __restrict__ Wq,
                            const float* __restrict__ Wk, const float* __restrict__ Wv,
                            unsigned short* __restrict__ xb, unsigned short* __restrict__ Wt) {
  __shared__ float t[32][33];
  if (blockIdx.x < 4096) {
    size_t i = ((size_t)blockIdx.x * 256 + threadIdx.x) * 8;
    const float4 a = *(const float4*)(x + i);
    const float4 b = *(const float4*)(x + i + 4);
    union { unsigned short us[8]; uint4 u; } o;
    o.us[0] = f2bf(a.x); o.us[1] = f2bf(a.y); o.us[2] = f2bf(a.z); o.us[3] = f2bf(a.w);
    o.us[4] = f2bf(b.x); o.us[5] = f2bf(b.y); o.us[6] = f2bf(b.z); o.us[7] = f2bf(b.w);
    *(uint4*)(xb + i) = o.u;
  } else {
    const int b = blockIdx.x - 4096;
    const int z = b >> 10;
    const int rem = b & 1023;
    const float* W = (z == 0) ? Wq : ((z == 1) ? Wk : Wv);
    unsigned short* o = Wt + (size_t)z * 1048576;
    const int k0 = (rem >> 5) * 32, n0 = (rem & 31) * 32;
    const int tx = threadIdx.x & 31, ty = threadIdx.x >> 5;
#pragma unroll
    for (int i = 0; i < 4; ++i)
      t[ty + i * 8][tx] = W[(size_t)(k0 + ty + i * 8) * 1024 + n0 + tx];
    __syncthreads();
#pragma unroll
    for (int i = 0; i < 4; ++i)
      o[(size_t)(n0 + ty + i * 8) * 1024 + k0 + tx] = f2bf(t[tx][ty + i * 8]);
  }
}

// ---------------- kernel 3: QKV GEMM (m97 geometry: 128x128, BK=64) ----------------
// 1-D grid 1536, XCD swizzle: W = (L%8)*192 + L/8. LDS T2 swizzle (rule-21).
// z=0 -> Q [bh][t][64] (pre-scaled by SCL2), z=1 -> K, z=2 -> Vt [bh][64][t] with
// sigma-permuted columns per 64-elem t-group (so attn PV reads one b128/frag).
// Q/K epilogue: wave quadrant staged in swizzled LDS slot -> coalesced dwordx4.
__global__ __launch_bounds__(256) void gemm_qkv(
    const unsigned short* __restrict__ xb, const unsigned short* __restrict__ Wt,
    unsigned short* __restrict__ Qb, unsigned short* __restrict__ Kb,
    unsigned short* __restrict__ Vtb) {
  __shared__ uint4 ldsab[2048];  // 32KB: A [0,16K), B [16K,32K); rows of 128B
  char* ldsc = (char*)ldsab;
  const int tid = threadIdx.x;
  const int lane = tid & 63;
  const int li = lane & 15, g = lane >> 4;
  const int wv = tid >> 6, wr = wv >> 1, wc = wv & 1;
  const int L = blockIdx.x;
  const int W = (L & 7) * 192 + (L >> 3);
  const int z = W >> 9;
  const int rem = W & 511;
  const int m0 = (rem >> 3) * 128, n0 = (rem & 7) * 128;
  const char* Abase = (const char*)xb;
  const char* Bbase = (const char*)(Wt + (size_t)z * 1048576);

  const f32x4 fz = {0.f, 0.f, 0.f, 0.f};
  f32x4 acc[4][4];
#pragma unroll
  for (int m = 0; m < 4; ++m)
#pragma unroll
    for (int n = 0; n < 4; ++n) acc[m][n] = fz;

  for (int kt = 0; kt < 16; ++kt) {
    __syncthreads();  // previous compute done reading LDS
#pragma unroll
    for (int i = 0; i < 4; ++i) {
      const int c = i * 256 + tid, r = c >> 3, cr = c & 7;
      gload16(Abase + (size_t)(m0 + r) * 2048 + kt * 128 + ((cr ^ (r & 7)) * 16),
              ldsc + c * 16);
      gload16(Bbase + (size_t)(n0 + r) * 2048 + kt * 128 + ((cr ^ (r & 7)) * 16),
              ldsc + 16384 + c * 16);
    }
    __syncthreads();  // vmcnt(0) drained -> LDS ready
#pragma unroll
    for (int ks = 0; ks < 2; ++ks) {
      bf16x8 a[4], b[4];
#pragma unroll
      for (int m = 0; m < 4; ++m) {
        const int ra = wr * 64 + m * 16 + li;
        a[m] = *(const bf16x8*)(ldsc + ra * 128 + (((ks * 4 + g) ^ (ra & 7)) * 16));
      }
#pragma unroll
      for (int n = 0; n < 4; ++n) {
        const int rb = wc * 64 + n * 16 + li;
        b[n] = *(const bf16x8*)(ldsc + 16384 + rb * 128 + (((ks * 4 + g) ^ (rb & 7)) * 16));
      }
#pragma unroll
      for (int m = 0; m < 4; ++m)
#pragma unroll
        for (int n = 0; n < 4; ++n)
          acc[m][n] = __builtin_amdgcn_mfma_f32_16x16x32_bf16(a[m], b[n], acc[m][n], 0, 0, 0);
    }
  }

  __syncthreads();  // compute reads of staging LDS done; reuse as transpose buf
  char* tb = ldsc + wv * 8192;
  if (z == 2) {
    // ---- Vt epilogue: transpose + sigma permutation through swizzled LDS ----
#pragma unroll
    for (int m = 0; m < 4; ++m)
#pragma unroll
      for (int n = 0; n < 4; ++n) {
        const int d_l = n * 16 + li;
#pragma unroll
        for (int rp = 0; rp < 2; ++rp) {
          const int t_l = m * 16 + g * 4 + rp * 2;
          const int t5 = t_l & 31;
          const int ks2 = t_l >> 5;
          const int rr = t5 & 15;
          const int gp = ((rr >> 3) & 1) * 2 + ((rr >> 2) & 1);
          const int j = (t5 & 3) + ((t5 >> 4) << 2);
          const unsigned lo = f2bf(acc[m][n][rp * 2]);
          const unsigned hi2 = f2bf(acc[m][n][rp * 2 + 1]);
          *(unsigned*)(tb + d_l * 128 + (((ks2 * 4 + gp) ^ (d_l & 7)) * 16) + j * 2) =
              lo | (hi2 << 16);
        }
      }
    __syncthreads();
    const int t0g = m0 + wr * 64;
    const int bI2 = t0g >> 11, tt2 = t0g & 2047;
    const int hh = (n0 + wc * 64) >> 6;
#pragma unroll
    for (int p2 = 0; p2 < 8; ++p2) {
      const int d_l = p2 * 8 + (lane >> 3);
      const int c8 = lane & 7;
      const uint4 v = *(const uint4*)(tb + d_l * 128 + ((c8 ^ (d_l & 7)) * 16));
      *(uint4*)((char*)Vtb +
                ((((size_t)(bI2 * 16 + hh) * 64 + d_l) * 2048 + tt2 + c8 * 8) * 2)) = v;
    }
  } else {
    // ---- Q/K epilogue: stage quadrant [t 64][d 64] in swizzled LDS slot ----
    const float sc = (z == 0) ? SCL2 : 1.0f;
#pragma unroll
    for (int m = 0; m < 4; ++m)
#pragma unroll
      for (int n = 0; n < 4; ++n) {
        const int ch = n * 2 + (li >> 3);
        const int eo = (li & 7) * 2;
#pragma unroll
        for (int r = 0; r < 4; ++r) {
          const int t_l = m * 16 + g * 4 + r;
          *(unsigned short*)(tb + t_l * 128 + ((ch ^ (t_l & 7)) * 16) + eo) =
              f2bf(acc[m][n][r] * sc);
        }
      }
    __syncthreads();
    const int t0g = m0 + wr * 64;
    const int bI = t0g >> 11, tt = t0g & 2047;
    const int h = (n0 + wc * 64) >> 6;
    unsigned short* dst = ((z == 0) ? Qb : Kb) + ((size_t)(bI * 16 + h) * 2048 + tt) * 64;
#pragma unroll
    for (int p = 0; p < 8; ++p) {
      const int t_l = p * 8 + (lane >> 3);
      const int c8 = lane & 7;
      const uint4 v = *(const uint4*)(tb + t_l * 128 + ((c8 ^ (t_l & 7)) * 16));
      *(uint4*)((char*)dst + t_l * 128 + c8 * 16) = v;
    }
  }
}

// ---------------- kernel 4: causal flash attention (deferred-PV pipeline) ----------------
// grid 512 x 512 threads (8 waves = 2 KV-groups x 4 q-waves). XCD swizzle as before.
// T15-lite: round r does [QK^T(cur) | PV(prev) | lsum(prev)] then SM(cur)->pb.
// PV(prev) is MFMA-independent filler that hides the QK^T->softmax latency; pb
// needs no ping-pong because PV(prev) reads it BEFORE SM(cur) overwrites it.
// V rotates over 3 LDS buffers (read one round later than K). K keeps 2.
// Per-group region 40KB: K0@0 K1@8K V0@16K V1@24K V2@32K; total 80KB -> 2 blocks/CU.
__global__ __launch_bounds__(512, 4) void attn_kernel(
    const unsigned short* __restrict__ Qb, const unsigned short* __restrict__ Kb,
    const unsigned short* __restrict__ Vtb, float* __restrict__ out) {
  __shared__ uint4 lds[5120];  // 80KB
  char* ldsc = (char*)lds;
  const int L = blockIdx.x;
  const int W = (L & 7) * 64 + (L >> 3);
  const int bh = W >> 3;
  const int qp = W & 7;
  const int tid = threadIdx.x;
  const int lane = tid & 63, wv = tid >> 6;
  const int grp = wv >> 2, wq = wv & 3;
  const int t256 = tid & 255;
  const int li = lane & 15, g = lane >> 4;

  char* gbase = ldsc + grp * 40960;

  const char* Qrow = (const char*)Qb + (size_t)bh * 2048 * 128;
  const char* Krow = (const char*)Kb + (size_t)bh * 2048 * 128;
  const char* Vrow = (const char*)Vtb + (size_t)bh * 64 * 4096;
  const int bI = bh >> 4, h = bh & 15;
  const f32x4 fz = {0.f, 0.f, 0.f, 0.f};

  // all-ones bf16x8 A-fragment for the l-sum MFMA
  union { unsigned int u[4]; bf16x8 v; } onesu;
  onesu.u[0] = 0x3F803F80u; onesu.u[1] = 0x3F803F80u;
  onesu.u[2] = 0x3F803F80u; onesu.u[3] = 0x3F803F80u;
  const bf16x8 ones = onesu.v;

  // stage tile t: K -> kbuf[t&1], V -> vbuf[t%3]; LDS linear dest, global src
  // pre-swizzled (involution cr ^= r&7) so swizzled reads see the right data.
  auto stage = [&](int t) {
    char* kb = gbase + (t & 1) * 8192;
    char* vb = gbase + 16384 + (t % 3) * 8192;
#pragma unroll
    for (int i = 0; i < 2; ++i) {
      const int c = i * 256 + t256, r = c >> 3, cr = c & 7;
      gload16(Krow + (size_t)(t * 64 + r) * 128 + ((cr ^ (r & 7)) * 16), kb + c * 16);
      gload16(Vrow + (size_t)r * 4096 + t * 128 + ((cr ^ (r & 7)) * 16), vb + c * 16);
    }
  };

  for (int half = 0; half < 2; ++half) {
    const int qt = half ? (15 - qp) : qp;   // 128-row tile id 0..15
    const int q0 = qt * 128;
    const int qw = q0 + wq * 32;
    const int hc = qt + 1;                  // rounds per group (even split of 2qt+2)
    const int kbeg = grp ? hc : 0;

    // Q fragments: qf[nq][ks] = Q[qw+nq*16+li][ks*32+g*8 .. +8]
    uint4 qf[2][2];
#pragma unroll
    for (int nq = 0; nq < 2; ++nq)
#pragma unroll
      for (int ks = 0; ks < 2; ++ks)
        qf[nq][ks] = *(const uint4*)(Qrow + (size_t)(qw + nq * 16 + li) * 128 + ks * 64 + g * 16);

    float mrow[2] = {-1e30f, -1e30f};
    float lrow[2] = {0.0f, 0.0f};
    f32x4 lsum[2] = {fz, fz};
    f32x4 ctx[4][2];
#pragma unroll
    for (int mtd = 0; mtd < 4; ++mtd)
#pragma unroll
      for (int nq = 0; nq < 2; ++nq) ctx[mtd][nq] = fz;

    bf16x8 pb[2][2];   // P of tile prev, scaled to exp2 units of mrow at pack time

    stage(kbeg);  // prologue

    for (int r = 0; r <= hc; ++r) {
      const int cur = kbeg + r;
      __syncthreads();  // drains prior stage's vmcnt; all waves past prior reads
      if (r + 1 < hc) stage(kbeg + r + 1);  // flies under this round's compute
      const bool doQ = (r < hc) && (cur * 64 <= qw + 31);
      const bool doP = (r >= 1) && ((cur - 1) * 64 <= qw + 31);

      // ---- QK^T(cur): S^T = K . Q^T, rows kk (4x16), cols q (2x16) ----
      f32x4 st[4][2];
      if (doQ) {
        const char* sK = gbase + (cur & 1) * 8192;
#pragma unroll
        for (int mt = 0; mt < 4; ++mt)
#pragma unroll
          for (int nq = 0; nq < 2; ++nq) st[mt][nq] = fz;
        __builtin_amdgcn_s_setprio(1);
#pragma unroll
        for (int ks = 0; ks < 2; ++ks) {
          bf16x8 kf[4];
#pragma unroll
          for (int mt = 0; mt < 4; ++mt) {
            const int rk = mt * 16 + li;
            kf[mt] = *(const bf16x8*)(sK + rk * 128 + (((ks * 4 + g) ^ (rk & 7)) * 16));
          }
#pragma unroll
          for (int mt = 0; mt < 4; ++mt)
#pragma unroll
            for (int nq = 0; nq < 2; ++nq)
              st[mt][nq] = __builtin_amdgcn_mfma_f32_16x16x32_bf16(
                  kf[mt], __builtin_bit_cast(bf16x8, qf[nq][ks]), st[mt][nq], 0, 0, 0);
        }
        __builtin_amdgcn_s_setprio(0);
      }

      // ---- PV(prev) + lsum(prev): independent MFMA filler (hides QKT->SM wait) ----
      if (doP) {
        const char* sV = gbase + 16384 + ((cur - 1) % 3) * 8192;
        __builtin_amdgcn_s_setprio(1);
#pragma unroll
        for (int ks2 = 0; ks2 < 2; ++ks2) {
#pragma unroll
          for (int mtd = 0; mtd < 4; ++mtd) {
            const int rd = mtd * 16 + li;
            const bf16x8 vf =
                *(const bf16x8*)(sV + rd * 128 + (((ks2 * 4 + g) ^ (rd & 7)) * 16));
#pragma unroll
            for (int nq = 0; nq < 2; ++nq)
              ctx[mtd][nq] = __builtin_amdgcn_mfma_f32_16x16x32_bf16(vf, pb[nq][ks2], ctx[mtd][nq], 0, 0, 0);
          }
#pragma unroll
          for (int nq = 0; nq < 2; ++nq)
            lsum[nq] = __builtin_amdgcn_mfma_f32_16x16x32_bf16(ones, pb[nq][ks2], lsum[nq], 0, 0, 0);
        }
        __builtin_amdgcn_s_setprio(0);
      }

      // ---- SM(cur): mask, gate-first defer-max, exp2, pack -> pb ----
      if (doQ) {
        const bool full = (cur * 64 + 63 <= qw);
#pragma unroll
        for (int nq = 0; nq < 2; ++nq) {
          float p[4][4];
          if (full) {
#pragma unroll
            for (int mt = 0; mt < 4; ++mt)
#pragma unroll
              for (int r2 = 0; r2 < 4; ++r2) p[mt][r2] = st[mt][nq][r2];
          } else {
            const int qg_ = qw + nq * 16 + li;
#pragma unroll
            for (int mt = 0; mt < 4; ++mt)
#pragma unroll
              for (int r2 = 0; r2 < 4; ++r2)
                p[mt][r2] = (cur * 64 + mt * 16 + g * 4 + r2 > qg_) ? -__builtin_inff()
                                                                    : st[mt][nq][r2];
          }
          // per-lane max via max3-fusable triples
          const float m1 = fmaxf(fmaxf(p[0][0], p[0][1]), p[0][2]);
          const float m2 = fmaxf(fmaxf(p[0][3], p[1][0]), p[1][1]);
          const float m3 = fmaxf(fmaxf(p[1][2], p[1][3]), p[2][0]);
          const float m4 = fmaxf(fmaxf(p[2][1], p[2][2]), p[2][3]);
          const float m5 = fmaxf(fmaxf(p[3][0], p[3][1]), p[3][2]);
          const float lmax = fmaxf(fmaxf(fmaxf(m1, m2), m3), fmaxf(fmaxf(m4, m5), p[3][3]));
          // gate-first defer-max (T13)
          if (!__all(lmax <= mrow[nq] + 8.0f)) {
            float tmax = fmaxf(lmax, __shfl_xor(lmax, 16, 64));
            tmax = fmaxf(tmax, __shfl_xor(tmax, 32, 64));
            const float mnew = fmaxf(mrow[nq], tmax);
            const float resc = __builtin_amdgcn_exp2f(mrow[nq] - mnew);
            mrow[nq] = mnew;
            lsum[nq] = lsum[nq] * resc;
#pragma unroll
            for (int mtd = 0; mtd < 4; ++mtd) ctx[mtd][nq] = ctx[mtd][nq] * resc;
          }
          const float mcur = mrow[nq];
#pragma unroll
          for (int mt = 0; mt < 4; ++mt)
#pragma unroll
            for (int r2 = 0; r2 < 4; ++r2)
              p[mt][r2] = __builtin_amdgcn_exp2f(p[mt][r2] - mcur);
          // pack P (plain casts -> v_cvt_pk_bf16_f32); consumed by PV next round
#pragma unroll
          for (int ks2 = 0; ks2 < 2; ++ks2) {
            union { __bf16 b[8]; bf16x8 v; } u;
#pragma unroll
            for (int r2 = 0; r2 < 4; ++r2) {
              u.b[r2] = (__bf16)p[2 * ks2][r2];
              u.b[4 + r2] = (__bf16)p[2 * ks2 + 1][r2];
            }
            pb[nq][ks2] = u.v;
          }
        }
      }
    }

    // extract denominators (all lsum rows equal; col = li = lane's q)
    lrow[0] = lsum[0][0];
    lrow[1] = lsum[1][0];

    // ---- merge group B partials into group A: ONE phase (both nq) ----
    __syncthreads();  // all compute done; staging buffers idle
    if (grp == 1) {
      char* mb = ldsc + 40960;
#pragma unroll
      for (int nqp = 0; nqp < 2; ++nqp)
#pragma unroll
        for (int mtd = 0; mtd < 4; ++mtd)
          *(f32x4*)(mb + (wq * 64 + lane) * 128 + nqp * 64 + ((mtd ^ (lane & 3)) * 16)) = ctx[mtd][nqp];
      if (g == 0) {
#pragma unroll
        for (int nqp = 0; nqp < 2; ++nqp) {
          ((float*)ldsc)[nqp * 64 + wq * 16 + li] = mrow[nqp];
          ((float*)(ldsc + 512))[nqp * 64 + wq * 16 + li] = lrow[nqp];
        }
      }
    }
    __syncthreads();
    if (grp == 0) {
      const char* mb = ldsc + 40960;
#pragma unroll
      for (int nqp = 0; nqp < 2; ++nqp) {
        const float mB = ((const float*)ldsc)[nqp * 64 + wq * 16 + li];
        const float lB = ((const float*)(ldsc + 512))[nqp * 64 + wq * 16 + li];
        const float mM = fmaxf(mrow[nqp], mB);
        const float cA = __builtin_amdgcn_exp2f(mrow[nqp] - mM);
        const float cB = __builtin_amdgcn_exp2f(mB - mM);
        const float inv = 1.0f / (lrow[nqp] * cA + lB * cB);
        const float fA = cA * inv, fB = cB * inv;
#pragma unroll
        for (int mtd = 0; mtd < 4; ++mtd) {
          const f32x4 cb = *(const f32x4*)(mb + (wq * 64 + lane) * 128 + nqp * 64 + ((mtd ^ (lane & 3)) * 16));
          ctx[mtd][nqp] = ctx[mtd][nqp] * fA + cb * fB;
        }
      }
    }
    __syncthreads();  // merge reads done before trb overwrites grp0 region

    // ---- epilogue (group A): ctx^T -> ctx via swizzled LDS, coalesced stores ----
    if (grp == 0) {
      float* trb = (float*)(ldsc + wq * 8192);
#pragma unroll
      for (int nqp = 0; nqp < 2; ++nqp)
#pragma unroll
        for (int mtd = 0; mtd < 4; ++mtd)
#pragma unroll
          for (int r2 = 0; r2 < 4; ++r2) {
            const int q = nqp * 16 + li;
            const int d = mtd * 16 + g * 4 + r2;
            trb[q * 64 + ((((d >> 2) ^ (q & 15)) << 2) | (d & 3))] = ctx[mtd][nqp][r2];
          }
    }
    __syncthreads();
    if (grp == 0) {
      const float* trb = (const float*)(ldsc + wq * 8192);
#pragma unroll
      for (int pass = 0; pass < 8; ++pass) {
        const int qr = pass * 4 + g;
        const float4 v = *(const float4*)&trb[qr * 64 + ((li ^ (qr & 15)) << 2)];
        *(float4*)(out + ((size_t)bI * 2048 + q0 + wq * 32 + qr) * 1024 + h * 64 + li * 4) = v;
      }
    }
    __syncthreads();  // epilogue reads done before next half's staging writes
  }
}

// ---------------- launcher ----------------
extern "C" void kernel_launch(void* const* d_in, const int* in_sizes, int n_in,
                              void* d_out, int out_size, void* d_ws, size_t ws_size,
                              hipStream_t stream) {
  (void)in_sizes; (void)n_in; (void)out_size; (void)ws_size;
  const float* x  = (const float*)d_in[0];
  const float* Wq = (const float*)d_in[1];
  const float* Wk = (const float*)d_in[2];
  const float* Wv = (const float*)d_in[3];
  float* out = (float*)d_out;
  char* ws = (char*)d_ws;
  unsigned short* xb  = (unsigned short*)ws;                    // 8192x1024 bf16  (16 MB)
  unsigned short* Wt  = (unsigned short*)(ws + 16777216);       // 3x 1024x1024 bf16 (6 MB)
  unsigned short* Qb  = (unsigned short*)(ws + 23068672);       // [64][2048][64] bf16
  unsigned short* Kb  = (unsigned short*)(ws + 39845888);       // [64][2048][64] bf16
  unsigned short* Vtb = (unsigned short*)(ws + 56623104);       // [64][64][2048] bf16 (sigma cols)

  hipLaunchKernelGGL(prep_kernel, dim3(4096 + 3072), dim3(256), 0, stream,
                     x, Wq, Wk, Wv, xb, Wt);
  hipLaunchKernelGGL(gemm_qkv, dim3(1536), dim3(256), 0, stream, xb, Wt, Qb, Kb, Vtb);
  hipLaunchKernelGGL(attn_kernel, dim3(512), dim3(512), 0, stream, Qb, Kb, Vtb, out);
}

// Round 15
// 164.511 us; speedup vs baseline: 2.0129x; 2.0129x over previous
//
#include <hip/hip_runtime.h>
#include <stdint.h>

typedef float f32x4 __attribute__((ext_vector_type(4)));
typedef __bf16 bf16x8 __attribute__((ext_vector_type(8)));

#define LOG2E 1.4426950408889634f
#define SCL2 (0.125f * LOG2E)   // 1/sqrt(64) * log2(e), folded into Q at GEMM epilogue

// RNE float -> bf16 bits (values are finite; NaN path not needed)
static __device__ __forceinline__ unsigned short f2bf(float f) {
  unsigned int u = __builtin_bit_cast(unsigned int, f);
  u += 0x7fffu + ((u >> 16) & 1u);
  return (unsigned short)(u >> 16);
}

static __device__ __forceinline__ void gload16(const void* g, void* l) {
  __builtin_amdgcn_global_load_lds(
      (const __attribute__((address_space(1))) unsigned int*)g,
      (__attribute__((address_space(3))) unsigned int*)l, 16, 0, 0);
}

// ---------------- kernel 1: fused {x fp32->bf16} + {W transpose->bf16} ----------------
__global__ void prep_kernel(const float* __restrict__ x, const float* __restrict__ Wq,
                            const float* __restrict__ Wk, const float* __restrict__ Wv,
                            unsigned short* __restrict__ xb, unsigned short* __restrict__ Wt) {
  __shared__ float t[32][33];
  if (blockIdx.x < 4096) {
    size_t i = ((size_t)blockIdx.x * 256 + threadIdx.x) * 8;
    const float4 a = *(const float4*)(x + i);
    const float4 b = *(const float4*)(x + i + 4);
    union { unsigned short us[8]; uint4 u; } o;
    o.us[0] = f2bf(a.x); o.us[1] = f2bf(a.y); o.us[2] = f2bf(a.z); o.us[3] = f2bf(a.w);
    o.us[4] = f2bf(b.x); o.us[5] = f2bf(b.y); o.us[6] = f2bf(b.z); o.us[7] = f2bf(b.w);
    *(uint4*)(xb + i) = o.u;
  } else {
    const int b = blockIdx.x - 4096;
    const int z = b >> 10;
    const int rem = b & 1023;
    const float* W = (z == 0) ? Wq : ((z == 1) ? Wk : Wv);
    unsigned short* o = Wt + (size_t)z * 1048576;
    const int k0 = (rem >> 5) * 32, n0 = (rem & 31) * 32;
    const int tx = threadIdx.x & 31, ty = threadIdx.x >> 5;
#pragma unroll
    for (int i = 0; i < 4; ++i)
      t[ty + i * 8][tx] = W[(size_t)(k0 + ty + i * 8) * 1024 + n0 + tx];
    __syncthreads();
#pragma unroll
    for (int i = 0; i < 4; ++i)
      o[(size_t)(n0 + ty + i * 8) * 1024 + k0 + tx] = f2bf(t[tx][ty + i * 8]);
  }
}

// ---------------- kernel 3: QKV GEMM (m97 geometry: 128x128, BK=64) ----------------
// 1-D grid 1536, XCD swizzle: W = (L%8)*192 + L/8. LDS T2 swizzle (rule-21).
// z=0 -> Q [bh][t][64] (pre-scaled by SCL2), z=1 -> K, z=2 -> Vt [bh][64][t] with
// sigma-permuted columns per 64-elem t-group (so attn PV reads one b128/frag):
//   element kk -> chunk (kk>>5)*4 + gp, slot (kk&3) + ((kk>>4)&1)*4,
//   gp = ((kk>>3)&1)*2 + ((kk>>2)&1)
// Q/K epilogue: wave's 64x64 quadrant staged in swizzled LDS slot -> 8 fully
// coalesced dwordx4 store passes (quadrant is 8KB contiguous in Qb/Kb).
__global__ __launch_bounds__(256) void gemm_qkv(
    const unsigned short* __restrict__ xb, const unsigned short* __restrict__ Wt,
    unsigned short* __restrict__ Qb, unsigned short* __restrict__ Kb,
    unsigned short* __restrict__ Vtb) {
  __shared__ uint4 ldsab[2048];  // 32KB: A [0,16K), B [16K,32K); rows of 128B
  char* ldsc = (char*)ldsab;
  const int tid = threadIdx.x;
  const int lane = tid & 63;
  const int li = lane & 15, g = lane >> 4;
  const int wv = tid >> 6, wr = wv >> 1, wc = wv & 1;
  const int L = blockIdx.x;
  const int W = (L & 7) * 192 + (L >> 3);
  const int z = W >> 9;
  const int rem = W & 511;
  const int m0 = (rem >> 3) * 128, n0 = (rem & 7) * 128;
  const char* Abase = (const char*)xb;
  const char* Bbase = (const char*)(Wt + (size_t)z * 1048576);

  const f32x4 fz = {0.f, 0.f, 0.f, 0.f};
  f32x4 acc[4][4];
#pragma unroll
  for (int m = 0; m < 4; ++m)
#pragma unroll
    for (int n = 0; n < 4; ++n) acc[m][n] = fz;

  for (int kt = 0; kt < 16; ++kt) {
    __syncthreads();  // previous compute done reading LDS
#pragma unroll
    for (int i = 0; i < 4; ++i) {
      const int c = i * 256 + tid, r = c >> 3, cr = c & 7;
      gload16(Abase + (size_t)(m0 + r) * 2048 + kt * 128 + ((cr ^ (r & 7)) * 16),
              ldsc + c * 16);
      gload16(Bbase + (size_t)(n0 + r) * 2048 + kt * 128 + ((cr ^ (r & 7)) * 16),
              ldsc + 16384 + c * 16);
    }
    __syncthreads();  // vmcnt(0) drained -> LDS ready
#pragma unroll
    for (int ks = 0; ks < 2; ++ks) {
      bf16x8 a[4], b[4];
#pragma unroll
      for (int m = 0; m < 4; ++m) {
        const int ra = wr * 64 + m * 16 + li;
        a[m] = *(const bf16x8*)(ldsc + ra * 128 + (((ks * 4 + g) ^ (ra & 7)) * 16));
      }
#pragma unroll
      for (int n = 0; n < 4; ++n) {
        const int rb = wc * 64 + n * 16 + li;
        b[n] = *(const bf16x8*)(ldsc + 16384 + rb * 128 + (((ks * 4 + g) ^ (rb & 7)) * 16));
      }
#pragma unroll
      for (int m = 0; m < 4; ++m)
#pragma unroll
        for (int n = 0; n < 4; ++n)
          acc[m][n] = __builtin_amdgcn_mfma_f32_16x16x32_bf16(a[m], b[n], acc[m][n], 0, 0, 0);
    }
  }

  __syncthreads();  // compute reads of staging LDS done; reuse as transpose buf
  char* tb = ldsc + wv * 8192;
  if (z == 2) {
    // ---- Vt epilogue: transpose + sigma permutation through swizzled LDS ----
#pragma unroll
    for (int m = 0; m < 4; ++m)
#pragma unroll
      for (int n = 0; n < 4; ++n) {
        const int d_l = n * 16 + li;
#pragma unroll
        for (int rp = 0; rp < 2; ++rp) {
          const int t_l = m * 16 + g * 4 + rp * 2;
          const int t5 = t_l & 31;
          const int ks2 = t_l >> 5;
          const int rr = t5 & 15;
          const int gp = ((rr >> 3) & 1) * 2 + ((rr >> 2) & 1);
          const int j = (t5 & 3) + ((t5 >> 4) << 2);
          const unsigned lo = f2bf(acc[m][n][rp * 2]);
          const unsigned hi2 = f2bf(acc[m][n][rp * 2 + 1]);
          *(unsigned*)(tb + d_l * 128 + (((ks2 * 4 + gp) ^ (d_l & 7)) * 16) + j * 2) =
              lo | (hi2 << 16);
        }
      }
    __syncthreads();
    const int t0g = m0 + wr * 64;
    const int bI2 = t0g >> 11, tt2 = t0g & 2047;
    const int hh = (n0 + wc * 64) >> 6;
#pragma unroll
    for (int p2 = 0; p2 < 8; ++p2) {
      const int d_l = p2 * 8 + (lane >> 3);
      const int c8 = lane & 7;
      const uint4 v = *(const uint4*)(tb + d_l * 128 + ((c8 ^ (d_l & 7)) * 16));
      *(uint4*)((char*)Vtb +
                ((((size_t)(bI2 * 16 + hh) * 64 + d_l) * 2048 + tt2 + c8 * 8) * 2)) = v;
    }
  } else {
    // ---- Q/K epilogue: stage quadrant [t 64][d 64] in swizzled LDS slot ----
    const float sc = (z == 0) ? SCL2 : 1.0f;
#pragma unroll
    for (int m = 0; m < 4; ++m)
#pragma unroll
      for (int n = 0; n < 4; ++n) {
        const int ch = n * 2 + (li >> 3);
        const int eo = (li & 7) * 2;
#pragma unroll
        for (int r = 0; r < 4; ++r) {
          const int t_l = m * 16 + g * 4 + r;
          *(unsigned short*)(tb + t_l * 128 + ((ch ^ (t_l & 7)) * 16) + eo) =
              f2bf(acc[m][n][r] * sc);
        }
      }
    __syncthreads();
    const int t0g = m0 + wr * 64;
    const int bI = t0g >> 11, tt = t0g & 2047;
    const int h = (n0 + wc * 64) >> 6;
    unsigned short* dst = ((z == 0) ? Qb : Kb) + ((size_t)(bI * 16 + h) * 2048 + tt) * 64;
#pragma unroll
    for (int p = 0; p < 8; ++p) {
      const int t_l = p * 8 + (lane >> 3);
      const int c8 = lane & 7;
      const uint4 v = *(const uint4*)(tb + t_l * 128 + ((c8 ^ (t_l & 7)) * 16));
      *(uint4*)((char*)dst + t_l * 128 + c8 * 16) = v;
    }
  }
}

// ---------------- kernel 4: causal flash attention ----------------
// grid 512 x 512 threads (8 waves = 2 KV-groups x 4 q-waves). XCD swizzle:
// W = (L%8)*64 + L/8 -> bh = W/8, qp = W%8 -> 128-row q-tile pair {qp,15-qp}.
// Per tile qt, KV range (2qt+2 tiles of 64) splits evenly between groups;
// 17 uniform rounds/block. nq=2 (wave owns 32 q-rows). gload_lds double-buffer
// staging w/ pre-swizzled source. Vt global layout is sigma-permuted (see gemm)
// so each PV A-fragment is ONE b128 read. l-sum via MFMA ones-trick. Gate-first
// defer-max. Single-phase merge of group B partials. setprio on MFMA (T5).
// NOTE (R13 lesson): do NOT extend st[]'s lifetime across another compute
// phase — live state here is within ~8 regs of the 128 unified budget; the
// deferred-PV variant spilled ~1GB/dispatch to scratch (FETCH 102->588MB).
__global__ __launch_bounds__(512, 4) void attn_kernel(
    const unsigned short* __restrict__ Qb, const unsigned short* __restrict__ Kb,
    const unsigned short* __restrict__ Vtb, float* __restrict__ out) {
  __shared__ uint4 lds[4096];  // 64KB: grp0 [0,32K) = {buf0 K|V, buf1 K|V}, grp1 [32K,64K)
  char* ldsc = (char*)lds;
  const int L = blockIdx.x;
  const int W = (L & 7) * 64 + (L >> 3);
  const int bh = W >> 3;
  const int qp = W & 7;
  const int tid = threadIdx.x;
  const int lane = tid & 63, wv = tid >> 6;
  const int grp = wv >> 2, wq = wv & 3;
  const int t256 = tid & 255;
  const int li = lane & 15, g = lane >> 4;

  char* gbase = ldsc + grp * 32768;

  const char* Qrow = (const char*)Qb + (size_t)bh * 2048 * 128;
  const char* Krow = (const char*)Kb + (size_t)bh * 2048 * 128;
  const char* Vrow = (const char*)Vtb + (size_t)bh * 64 * 4096;
  const int bI = bh >> 4, h = bh & 15;
  const f32x4 fz = {0.f, 0.f, 0.f, 0.f};

  // all-ones bf16x8 A-fragment for the l-sum MFMA
  union { unsigned int u[4]; bf16x8 v; } onesu;
  onesu.u[0] = 0x3F803F80u; onesu.u[1] = 0x3F803F80u;
  onesu.u[2] = 0x3F803F80u; onesu.u[3] = 0x3F803F80u;
  const bf16x8 ones = onesu.v;

  // stage one 64-row K tile + V tile into buffer b, LDS linear, global src
  // pre-swizzled (involution cr ^= r&7) so swizzled reads see the right data.
  auto stage = [&](int b, int kt) {
#pragma unroll
    for (int i = 0; i < 2; ++i) {
      const int c = i * 256 + t256, r = c >> 3, cr = c & 7;
      gload16(Krow + (size_t)(kt * 64 + r) * 128 + ((cr ^ (r & 7)) * 16),
              gbase + b * 16384 + c * 16);
      gload16(Vrow + (size_t)r * 4096 + kt * 128 + ((cr ^ (r & 7)) * 16),
              gbase + b * 16384 + 8192 + c * 16);
    }
  };

  for (int half = 0; half < 2; ++half) {
    const int qt = half ? (15 - qp) : qp;   // 128-row tile id 0..15
    const int q0 = qt * 128;
    const int qw = q0 + wq * 32;
    const int hc = qt + 1;                  // rounds per group (even split of 2qt+2)
    const int kbeg = grp ? hc : 0;

    // Q fragments: qf[nq][ks] = Q[qw+nq*16+li][ks*32+g*8 .. +8]
    uint4 qf[2][2];
#pragma unroll
    for (int nq = 0; nq < 2; ++nq)
#pragma unroll
      for (int ks = 0; ks < 2; ++ks)
        qf[nq][ks] = *(const uint4*)(Qrow + (size_t)(qw + nq * 16 + li) * 128 + ks * 64 + g * 16);

    float mrow[2] = {-1e30f, -1e30f};
    float lrow[2] = {0.0f, 0.0f};
    f32x4 lsum[2] = {fz, fz};
    f32x4 ctx[4][2];
#pragma unroll
    for (int mtd = 0; mtd < 4; ++mtd)
#pragma unroll
      for (int nq = 0; nq < 2; ++nq) ctx[mtd][nq] = fz;

    stage(0, kbeg);  // prologue: buf0 <- first tile of this group's range

    for (int it = 0; it < hc; ++it) {
      const int kt = kbeg + it;
      __syncthreads();  // drains vmcnt -> buf[it&1] ready; prev compute done
      if (it + 1 < hc) stage((it + 1) & 1, kt + 1);  // flies under compute
      if (kt * 64 > qw + 31) continue;  // fully masked for this wave

      const char* sK = gbase + (it & 1) * 16384;
      const char* sV = sK + 8192;

      // ---- S^T = K . Q^T : rows kk (4 x 16), cols q (2 x 16) ----
      f32x4 st[4][2];
#pragma unroll
      for (int mt = 0; mt < 4; ++mt)
#pragma unroll
        for (int nq = 0; nq < 2; ++nq) st[mt][nq] = fz;
      __builtin_amdgcn_s_setprio(1);
#pragma unroll
      for (int ks = 0; ks < 2; ++ks) {
        bf16x8 kf[4];
#pragma unroll
        for (int mt = 0; mt < 4; ++mt) {
          const int rk = mt * 16 + li;
          kf[mt] = *(const bf16x8*)(sK + rk * 128 + (((ks * 4 + g) ^ (rk & 7)) * 16));
        }
#pragma unroll
        for (int mt = 0; mt < 4; ++mt)
#pragma unroll
          for (int nq = 0; nq < 2; ++nq)
            st[mt][nq] = __builtin_amdgcn_mfma_f32_16x16x32_bf16(
                kf[mt], __builtin_bit_cast(bf16x8, qf[nq][ks]), st[mt][nq], 0, 0, 0);
      }
      __builtin_amdgcn_s_setprio(0);

      // ---- online softmax per nq (lane q = qw+nq*16+li; kk = kt*64+mt*16+g*4+r) ----
      const bool full = (kt * 64 + 63 <= qw);
      bf16x8 pb[2][2];
#pragma unroll
      for (int nq = 0; nq < 2; ++nq) {
        float p[4][4];
        if (full) {
#pragma unroll
          for (int mt = 0; mt < 4; ++mt)
#pragma unroll
            for (int r = 0; r < 4; ++r) p[mt][r] = st[mt][nq][r];
        } else {
          const int qg_ = qw + nq * 16 + li;
#pragma unroll
          for (int mt = 0; mt < 4; ++mt)
#pragma unroll
            for (int r = 0; r < 4; ++r)
              p[mt][r] = (kt * 64 + mt * 16 + g * 4 + r > qg_) ? -__builtin_inff()
                                                               : st[mt][nq][r];
        }
        // per-lane max via max3-fusable triples (no cross-lane yet)
        const float m1 = fmaxf(fmaxf(p[0][0], p[0][1]), p[0][2]);
        const float m2 = fmaxf(fmaxf(p[0][3], p[1][0]), p[1][1]);
        const float m3 = fmaxf(fmaxf(p[1][2], p[1][3]), p[2][0]);
        const float m4 = fmaxf(fmaxf(p[2][1], p[2][2]), p[2][3]);
        const float m5 = fmaxf(fmaxf(p[3][0], p[3][1]), p[3][2]);
        const float lmax = fmaxf(fmaxf(fmaxf(m1, m2), m3), fmaxf(fmaxf(m4, m5), p[3][3]));
        // gate-first defer-max (T13): group max exceeds threshold iff some
        // lane's local max does -> shfls only inside the rare branch.
        if (!__all(lmax <= mrow[nq] + 8.0f)) {
          float tmax = fmaxf(lmax, __shfl_xor(lmax, 16, 64));
          tmax = fmaxf(tmax, __shfl_xor(tmax, 32, 64));
          const float mnew = fmaxf(mrow[nq], tmax);
          const float resc = __builtin_amdgcn_exp2f(mrow[nq] - mnew);
          mrow[nq] = mnew;
          lsum[nq] = lsum[nq] * resc;
#pragma unroll
          for (int mtd = 0; mtd < 4; ++mtd) ctx[mtd][nq] = ctx[mtd][nq] * resc;
        }
        const float mcur = mrow[nq];
#pragma unroll
        for (int mt = 0; mt < 4; ++mt)
#pragma unroll
          for (int r = 0; r < 4; ++r)
            p[mt][r] = __builtin_amdgcn_exp2f(p[mt][r] - mcur);
        // pack P (plain casts -> v_cvt_pk_bf16_f32); l-sum comes from MFMA below
#pragma unroll
        for (int ks2 = 0; ks2 < 2; ++ks2) {
          union { __bf16 b[8]; bf16x8 v; } u;
#pragma unroll
          for (int r = 0; r < 4; ++r) {
            u.b[r] = (__bf16)p[2 * ks2][r];
            u.b[4 + r] = (__bf16)p[2 * ks2 + 1][r];
          }
          pb[nq][ks2] = u.v;
        }
      }

      // ---- PV + l-sum: ctx^T[d][q] += Vt . P^T  (sigma layout: 1 b128/frag) ----
      __builtin_amdgcn_s_setprio(1);
#pragma unroll
      for (int ks2 = 0; ks2 < 2; ++ks2) {
#pragma unroll
        for (int mtd = 0; mtd < 4; ++mtd) {
          const int rd = mtd * 16 + li;
          const bf16x8 vf =
              *(const bf16x8*)(sV + rd * 128 + (((ks2 * 4 + g) ^ (rd & 7)) * 16));
#pragma unroll
          for (int nq = 0; nq < 2; ++nq)
            ctx[mtd][nq] = __builtin_amdgcn_mfma_f32_16x16x32_bf16(vf, pb[nq][ks2], ctx[mtd][nq], 0, 0, 0);
        }
#pragma unroll
        for (int nq = 0; nq < 2; ++nq)
          lsum[nq] = __builtin_amdgcn_mfma_f32_16x16x32_bf16(ones, pb[nq][ks2], lsum[nq], 0, 0, 0);
      }
      __builtin_amdgcn_s_setprio(0);
    }

    // extract denominators (all lsum rows equal; col = li = lane's q)
    lrow[0] = lsum[0][0];
    lrow[1] = lsum[1][0];

    // ---- merge group B partials into group A: ONE phase (both nq) ----
    __syncthreads();  // all compute done; staging buffers idle
    if (grp == 1) {
      char* mb = ldsc + 32768;
#pragma unroll
      for (int nqp = 0; nqp < 2; ++nqp)
#pragma unroll
        for (int mtd = 0; mtd < 4; ++mtd)
          *(f32x4*)(mb + (wq * 64 + lane) * 128 + nqp * 64 + ((mtd ^ (lane & 3)) * 16)) = ctx[mtd][nqp];
      if (g == 0) {
#pragma unroll
        for (int nqp = 0; nqp < 2; ++nqp) {
          ((float*)ldsc)[nqp * 64 + wq * 16 + li] = mrow[nqp];
          ((float*)(ldsc + 512))[nqp * 64 + wq * 16 + li] = lrow[nqp];
        }
      }
    }
    __syncthreads();
    if (grp == 0) {
      const char* mb = ldsc + 32768;
#pragma unroll
      for (int nqp = 0; nqp < 2; ++nqp) {
        const float mB = ((const float*)ldsc)[nqp * 64 + wq * 16 + li];
        const float lB = ((const float*)(ldsc + 512))[nqp * 64 + wq * 16 + li];
        const float mM = fmaxf(mrow[nqp], mB);
        const float cA = __builtin_amdgcn_exp2f(mrow[nqp] - mM);
        const float cB = __builtin_amdgcn_exp2f(mB - mM);
        const float inv = 1.0f / (lrow[nqp] * cA + lB * cB);
        const float fA = cA * inv, fB = cB * inv;
#pragma unroll
        for (int mtd = 0; mtd < 4; ++mtd) {
          const f32x4 cb = *(const f32x4*)(mb + (wq * 64 + lane) * 128 + nqp * 64 + ((mtd ^ (lane & 3)) * 16));
          ctx[mtd][nqp] = ctx[mtd][nqp] * fA + cb * fB;
        }
      }
    }
    __syncthreads();  // merge reads done before trb overwrites grp0 region

    // ---- epilogue (group A): ctx^T -> ctx via swizzled LDS, coalesced stores ----
    if (grp == 0) {
      float* trb = (float*)(ldsc + wq * 8192);
#pragma unroll
      for (int nqp = 0; nqp < 2; ++nqp)
#pragma unroll
        for (int mtd = 0; mtd < 4; ++mtd)
#pragma unroll
          for (int r = 0; r < 4; ++r) {
            const int q = nqp * 16 + li;
            const int d = mtd * 16 + g * 4 + r;
            trb[q * 64 + ((((d >> 2) ^ (q & 15)) << 2) | (d & 3))] = ctx[mtd][nqp][r];
          }
    }
    __syncthreads();
    if (grp == 0) {
      const float* trb = (const float*)(ldsc + wq * 8192);
#pragma unroll
      for (int pass = 0; pass < 8; ++pass) {
        const int qr = pass * 4 + g;
        const float4 v = *(const float4*)&trb[qr * 64 + ((li ^ (qr & 15)) << 2)];
        *(float4*)(out + ((size_t)bI * 2048 + q0 + wq * 32 + qr) * 1024 + h * 64 + li * 4) = v;
      }
    }
    __syncthreads();  // epilogue reads done before next half's staging writes
  }
}

// ---------------- launcher ----------------
extern "C" void kernel_launch(void* const* d_in, const int* in_sizes, int n_in,
                              void* d_out, int out_size, void* d_ws, size_t ws_size,
                              hipStream_t stream) {
  (void)in_sizes; (void)n_in; (void)out_size; (void)ws_size;
  const float* x  = (const float*)d_in[0];
  const float* Wq = (const float*)d_in[1];
  const float* Wk = (const float*)d_in[2];
  const float* Wv = (const float*)d_in[3];
  float* out = (float*)d_out;
  char* ws = (char*)d_ws;
  unsigned short* xb  = (unsigned short*)ws;                    // 8192x1024 bf16  (16 MB)
  unsigned short* Wt  = (unsigned short*)(ws + 16777216);       // 3x 1024x1024 bf16 (6 MB)
  unsigned short* Qb  = (unsigned short*)(ws + 23068672);       // [64][2048][64] bf16
  unsigned short* Kb  = (unsigned short*)(ws + 39845888);       // [64][2048][64] bf16
  unsigned short* Vtb = (unsigned short*)(ws + 56623104);       // [64][64][2048] bf16 (sigma cols)

  hipLaunchKernelGGL(prep_kernel, dim3(4096 + 3072), dim3(256), 0, stream,
                     x, Wq, Wk, Wv, xb, Wt);
  hipLaunchKernelGGL(gemm_qkv, dim3(1536), dim3(256), 0, stream, xb, Wt, Qb, Kb, Vtb);
  hipLaunchKernelGGL(attn_kernel, dim3(512), dim3(512), 0, stream, Qb, Kb, Vtb, out);
}